// Round 15
// baseline (81.284 us; speedup 1.0000x reference)
//
#include <hip/hip_runtime.h>
#include <stdint.h>

// Problem: B,T,C = 2,768,64; N_HEAD=64 -> head_dim=1; fp32 buffers.
// Model (R11 probe + R12/R13 flat + R14 regress): inner iter ~65 cyc with 2
// exps -> v_exp_f32 ~ 32 cyc/wave64 (1/8-rate trans). R14's SCALAR half-poly
// regressed (serial 7-op chain, unpackable). R15: BOTH exps via fully-packed
// v2f polynomial (pk_sub/3x pk_fma + 2 rndne + 2 cvt + 2 lshl_add ~= 20 cyc
// VALU per 2 exps, ZERO trans). Exact exponent-field add (sc in [-30,3]
// after ALiBi skip). Everything else identical to R13 (75.39 best).
constexpr int Tc = 768;
constexpr int Hc = 64;
constexpr int Bc = 2;
constexpr float LOG2E = 1.44269504088896f;
constexpr size_t SLAB = (size_t)Bc * Hc * Tc;   // 98304 floats per slab

typedef float v2f __attribute__((ext_vector_type(2)));
typedef float v4f __attribute__((ext_vector_type(4)));

// ---------------------------------------------------------------------------
// Kernel 1: projection into transposed slabs (measured ~3 us, R7).
// ---------------------------------------------------------------------------
__global__ __launch_bounds__(256) void proj_kernel(
    const float* __restrict__ x, const float* __restrict__ W,
    const float* __restrict__ vtmp, const float* __restrict__ ptmp,
    float* __restrict__ qs, float* __restrict__ ks, float* __restrict__ vs)
{
    const int lane = threadIdx.x & 63;
    const int w    = __builtin_amdgcn_readfirstlane(threadIdx.x >> 6);
    const int g    = blockIdx.x * 64 + lane;     // global row in [0,1536)
    const int bh0  = (g / Tc) * Hc;              // b*64 (64 | 768: no straddle)
    const int t    = g % Tc;
    const int h    = blockIdx.y * 4 + w;         // wave-uniform head

    float xr[64];
    const v4f* xp = (const v4f*)(x + (size_t)g * 64);
#pragma unroll
    for (int c = 0; c < 16; ++c) ((v4f*)xr)[c] = xp[c];

    const float* __restrict__ wq = W + h * 64;
    const float* __restrict__ wk = W + (64 + h) * 64;
    float aq = 0.f, ak = 0.f;
#pragma unroll
    for (int c = 0; c < 64; ++c) {               // constant indices only
        aq = fmaf(xr[c], wq[c], aq);
        ak = fmaf(xr[c], wk[c], ak);
    }
    const size_t o = (size_t)(bh0 + h) * Tc + t;   // lane-coalesced
    qs[o] = aq * LOG2E;
    ks[o] = ak;
    vs[o] = x[(size_t)g * 64 + h] * vtmp[h] * ptmp[h];   // global reload, not xr[h]
}

// Fully-packed VALU exp2 for 2 values: 2x v_rndne + 1 pk_sub + 3 pk_fma +
// 2x cvt_i32 + 2x lshl_add. Minimax cubic on [-0.5,0.5], rel err <= ~3e-4.
// Valid for x in [-120, 120] (no denormal/overflow in exponent-field add).
__device__ __forceinline__ v2f fast_exp2_v2(v2f x) {
    float n0 = __builtin_rintf(x.x);             // v_rndne_f32
    float n1 = __builtin_rintf(x.y);
    v2f n; n.x = n0; n.y = n1;
    v2f r = x - n;                               // v_pk_add_f32 (neg)
    const v2f c3 = {0.0558282f, 0.0558282f};
    const v2f c2 = {0.2401397f, 0.2401397f};
    const v2f c1 = {0.6931472f, 0.6931472f};
    const v2f c0 = {1.0f, 1.0f};
    v2f p = r * c3 + c2;                         // v_pk_fma_f32
    p = r * p + c1;
    p = r * p + c0;
    v2f out;
    out.x = __int_as_float(__float_as_int(p.x) + (((int)n0) << 23));
    out.y = __int_as_float(__float_as_int(p.y) + (((int)n1) << 23));
    return out;
}

// ---------------------------------------------------------------------------
// Kernel 2: attention (R13 structure). Block = (rt: 64 rows, h, b); lane =
// row; 4 waves = 4 j-quarters. Per 16-j chunk: k[16], v[16] from ws; 8 packed
// iters: pk math + PACKED POLY exp (zero trans). Wave-uniform chunk classes:
// [skip] | past (no min) | mixed (full) | future (bias=0).
// grid (12,64,2) = 1536 = 6 blocks/CU, 24 waves/CU.
// ---------------------------------------------------------------------------
__global__ __launch_bounds__(256, 6) void attn_kernel(
    const float* __restrict__ qs, const float* __restrict__ ks,
    const float* __restrict__ vs, float* __restrict__ out)
{
    const int tid  = threadIdx.x;
    const int lane = tid & 63;
    const int w    = __builtin_amdgcn_readfirstlane(tid >> 6);
    const int rt   = blockIdx.x;   // 0..11 (64-row tile)
    const int h    = blockIdx.y;
    const int b    = blockIdx.z;
    const int bh   = b * Hc + h;

    __shared__ float psum[4][64], pacc[4][64];   // 2 KB only

    const float* __restrict__ kp = ks + (size_t)bh * Tc;
    const float* __restrict__ vp = vs + (size_t)bh * Tc;

    const int i = rt * 64 + lane;            // this lane's query row
    const float q = qs[(size_t)bh * Tc + i]; // coalesced, log2e folded
    // slopes[h] = 2^(-(h+1)/8) (H=64), folded with log2(e)
    const float slope2 = exp2f(-0.125f * (float)(h + 1)) * LOG2E;

    v2f cu2[8];                              // {slope*(2u), slope*(2u+1)}
#pragma unroll
    for (int u = 0; u < 8; ++u) {
        cu2[u].x = slope2 * (float)(2 * u);
        cu2[u].y = slope2 * (float)(2 * u + 1);
    }

    const int j0 = w * (Tc / 4);             // this wave's 192-j quarter
    // ALiBi distant-past skip: chunks entirely below i_min - 28/slope2
    int c0 = 0;
    {
        const int jskip = rt * 64 - (int)(28.f / slope2);
        if (jskip > j0) {
            c0 = (jskip - j0) >> 4;
            if (c0 > 12) c0 = 12;
        }
    }

    v2f sum2 = {0.f, 0.f}, acc2 = {0.f, 0.f};
    const v2f q2 = {q, q};

    for (int c = c0; c < 12; ++c) {          // chunks of 16 j (8 packed iters)
        const int jc = j0 + 16 * c;          // wave-uniform
        float kk[16], vv[16];
        const float* __restrict__ kc = kp + jc;
        const float* __restrict__ vc = vp + jc;
#pragma unroll
        for (int u = 0; u < 16; ++u) { kk[u] = kc[u]; vv[u] = vc[u]; }

        const float mb = slope2 * (float)(jc - i);
        const v2f mb2 = {mb, mb};
        if (jc >= rt * 64 + 64) {
            // FUTURE: all j > all i -> bias = 0
#pragma unroll
            for (int u = 0; u < 8; ++u) {
                v2f k2 = {kk[2 * u], kk[2 * u + 1]};
                v2f v2 = {vv[2 * u], vv[2 * u + 1]};
                v2f sc = q2 * k2;            // v_pk_mul_f32
                v2f e = fast_exp2_v2(sc);    // packed VALU poly, zero trans
                sum2 += e;
                acc2 = e * v2 + acc2;        // v_pk_fma_f32
            }
        } else if (jc + 15 < rt * 64) {
            // PAST: all j < all i -> bias = slope*(j-i) (no min)
#pragma unroll
            for (int u = 0; u < 8; ++u) {
                v2f k2 = {kk[2 * u], kk[2 * u + 1]};
                v2f v2 = {vv[2 * u], vv[2 * u + 1]};
                v2f bias = mb2 + cu2[u];
                v2f sc = q2 * k2 + bias;
                v2f e = fast_exp2_v2(sc);
                sum2 += e;
                acc2 = e * v2 + acc2;
            }
        } else {
            // MIXED (diagonal band): full path with min
#pragma unroll
            for (int u = 0; u < 8; ++u) {
                v2f k2 = {kk[2 * u], kk[2 * u + 1]};
                v2f v2 = {vv[2 * u], vv[2 * u + 1]};
                v2f t2 = mb2 + cu2[u];
                v2f bias;
                bias.x = fminf(t2.x, 0.f);
                bias.y = fminf(t2.y, 0.f);
                v2f sc = q2 * k2 + bias;
                v2f e = fast_exp2_v2(sc);
                sum2 += e;
                acc2 = e * v2 + acc2;
            }
        }
    }
    psum[w][lane] = sum2.x + sum2.y;
    pacc[w][lane] = acc2.x + acc2.y;
    __syncthreads();

    // ---- combine 4 j-quarters, write out ----
    if (tid < 64) {
        float s = psum[0][lane] + psum[1][lane] + psum[2][lane] + psum[3][lane];
        float a = pacc[0][lane] + pacc[1][lane] + pacc[2][lane] + pacc[3][lane];
        out[((size_t)(b * Tc + rt * 64 + lane)) * 64 + h] =
            a * __builtin_amdgcn_rcpf(s);
    }
}

extern "C" void kernel_launch(void* const* d_in, const int* in_sizes, int n_in,
                              void* d_out, int out_size, void* d_ws, size_t ws_size,
                              hipStream_t stream) {
    const float* x    = (const float*)d_in[0];
    const float* W    = (const float*)d_in[1];
    const float* vtmp = (const float*)d_in[2];
    const float* ptmp = (const float*)d_in[3];
    float* out = (float*)d_out;

    float* qsl = (float*)d_ws;
    float* ksl = qsl + SLAB;
    float* vsl = ksl + SLAB;

    proj_kernel<<<dim3(24, 16), 256, 0, stream>>>(x, W, vtmp, ptmp, qsl, ksl, vsl);
    attn_kernel<<<dim3(12, Hc, Bc), 256, 0, stream>>>(qsl, ksl, vsl, out);
}

// Round 16
// 76.394 us; speedup vs baseline: 1.0640x; 1.0640x over previous
//
#include <hip/hip_runtime.h>
#include <stdint.h>

// Problem: B,T,C = 2,768,64; N_HEAD=64 -> head_dim=1; fp32 buffers.
// R13/14/15 discrimination: exp2-on-trans is already optimal per pair; the
// wall is the O(T^2) exp COUNT. R16: moment factorization. head_dim=1 =>
// e^(q k) = sum_m (q^m/m!) k^m (deg-7 Taylor, |qk|<=0.6, rel err <=5e-6).
// Off-diagonal j-blocks collapse to 8 moments: future via suffix moments
// (16 FMA/row total), past via per-block decayed moments (1 exp + 16 FMA
// per 64-j block; decay factorized 2^(s(j-eB)) * 2^(s(eB-i))). Only the
// diagonal 64-j tile stays exact. Exps/row: 768 -> ~70.
constexpr int Tc = 768;
constexpr int Hc = 64;
constexpr int Bc = 2;
constexpr int NT = 12;               // 64-row/col tiles per sequence
constexpr float LOG2E = 1.44269504088896f;
constexpr float LN2   = 0.69314718056f;
constexpr size_t SLAB = (size_t)Bc * Hc * Tc;     // 98304 floats per slab
constexpr size_t MOMSZ = (size_t)Bc * Hc * NT * 16; // 24576 floats per table

typedef float v2f __attribute__((ext_vector_type(2)));
typedef float v4f __attribute__((ext_vector_type(4)));

// ---------------------------------------------------------------------------
// Kernel 1: projection into transposed slabs (measured ~3 us, R7).
// ---------------------------------------------------------------------------
__global__ __launch_bounds__(256) void proj_kernel(
    const float* __restrict__ x, const float* __restrict__ W,
    const float* __restrict__ vtmp, const float* __restrict__ ptmp,
    float* __restrict__ qs, float* __restrict__ ks, float* __restrict__ vs)
{
    const int lane = threadIdx.x & 63;
    const int w    = __builtin_amdgcn_readfirstlane(threadIdx.x >> 6);
    const int g    = blockIdx.x * 64 + lane;     // global row in [0,1536)
    const int bh0  = (g / Tc) * Hc;              // b*64 (64 | 768: no straddle)
    const int t    = g % Tc;
    const int h    = blockIdx.y * 4 + w;         // wave-uniform head

    float xr[64];
    const v4f* xp = (const v4f*)(x + (size_t)g * 64);
#pragma unroll
    for (int c = 0; c < 16; ++c) ((v4f*)xr)[c] = xp[c];

    const float* __restrict__ wq = W + h * 64;
    const float* __restrict__ wk = W + (64 + h) * 64;
    float aq = 0.f, ak = 0.f;
#pragma unroll
    for (int c = 0; c < 64; ++c) {               // constant indices only
        aq = fmaf(xr[c], wq[c], aq);
        ak = fmaf(xr[c], wk[c], ak);
    }
    const size_t o = (size_t)(bh0 + h) * Tc + t;   // lane-coalesced
    qs[o] = aq * LOG2E;
    ks[o] = ak;
    vs[o] = x[(size_t)g * 64 + h] * vtmp[h] * ptmp[h];   // global reload, not xr[h]
}

// 64-lane DPP sum; total in lane 63 (verified R3/R8).
__device__ __forceinline__ float dpp_reduce_add(float v) {
    v += __int_as_float(__builtin_amdgcn_update_dpp(0, __float_as_int(v), 0x111, 0xf, 0xf, true));
    v += __int_as_float(__builtin_amdgcn_update_dpp(0, __float_as_int(v), 0x112, 0xf, 0xf, true));
    v += __int_as_float(__builtin_amdgcn_update_dpp(0, __float_as_int(v), 0x114, 0xf, 0xf, true));
    v += __int_as_float(__builtin_amdgcn_update_dpp(0, __float_as_int(v), 0x118, 0xf, 0xf, true));
    v += __int_as_float(__builtin_amdgcn_update_dpp(0, __float_as_int(v), 0x142, 0xf, 0xf, true));
    v += __int_as_float(__builtin_amdgcn_update_dpp(0, __float_as_int(v), 0x143, 0xf, 0xf, true));
    return v;
}

// ---------------------------------------------------------------------------
// Kernel 1.5: per-(b,h) block moments. For each 64-j block B (eB = B*64+63):
//   FM[m]  = sum_j k^m          FMv[m]  = sum_j k^m v
//   PM[m]  = sum_j k^m 2^(s(j-eB))   PMv[m] = ... * v     (s = slope*log2e)
// Writes: PMc[bh][B][0..7]=PM, [8..15]=PMv;
//         SufF[bh][rt][0..7]=sum_{B>rt}FM, [8..15]=sum FMv.
// grid 128 (=bh) x 256 (4 waves x 3 blocks each).
// ---------------------------------------------------------------------------
__global__ __launch_bounds__(256) void moments_kernel(
    const float* __restrict__ ks, const float* __restrict__ vs,
    float* __restrict__ SufF, float* __restrict__ PMc)
{
    const int bh   = blockIdx.x;
    const int h    = bh & 63;
    const int lane = threadIdx.x & 63;
    const int w    = __builtin_amdgcn_readfirstlane(threadIdx.x >> 6);
    const float slope2 = exp2f(-0.125f * (float)(h + 1)) * LOG2E;

    __shared__ float FMs[NT][16];

    for (int B = w; B < NT; B += 4) {
        const int j = B * 64 + lane;
        const float k = ks[(size_t)bh * Tc + j];
        const float v = vs[(size_t)bh * Tc + j];
        const float lf = exp2f(slope2 * (float)(lane - 63));  // 2^(s(j-eB)) <= 1
        float km = 1.f;
#pragma unroll
        for (int m = 0; m < 8; ++m) {
            float r0 = dpp_reduce_add(km);
            float r1 = dpp_reduce_add(km * v);
            float r2 = dpp_reduce_add(km * lf);
            float r3 = dpp_reduce_add(km * lf * v);
            if (lane == 63) {
                FMs[B][m]     = r0;
                FMs[B][8 + m] = r1;
                PMc[(size_t)bh * (NT * 16) + B * 16 + m]     = r2;
                PMc[(size_t)bh * (NT * 16) + B * 16 + 8 + m] = r3;
            }
            km *= k;
        }
    }
    __syncthreads();
    // suffix over blocks: SufF[rt][idx] = sum_{B>rt} FMs[B][idx]
    if (threadIdx.x < NT * 16) {
        const int rt = threadIdx.x >> 4;
        const int idx = threadIdx.x & 15;
        float s = 0.f;
        for (int B = rt + 1; B < NT; ++B) s += FMs[B][idx];
        SufF[(size_t)bh * (NT * 16) + rt * 16 + idx] = s;
    }
}

// ---------------------------------------------------------------------------
// Kernel 2: attention via moments. grid (3,64,2) x 256: block = (4 row-tiles,
// h, b); wave w -> tile rt = bx*4+w; lane = row i = rt*64+lane.
//  future : 16 FMA with SufF[bh][rt]      (covers all j >= (rt+1)*64)
//  past   : per block B<rt (ALiBi-skipped): 1 exp + 16 FMA with PMc[bh][B]
//  diag   : exact R13 inner over the 64-j tile (packed 2-j, min-bias)
// ---------------------------------------------------------------------------
__global__ __launch_bounds__(256) void attn_kernel(
    const float* __restrict__ qs, const float* __restrict__ ks,
    const float* __restrict__ vs, const float* __restrict__ SufF,
    const float* __restrict__ PMc, float* __restrict__ out)
{
    const int tid  = threadIdx.x;
    const int lane = tid & 63;
    const int w    = __builtin_amdgcn_readfirstlane(tid >> 6);
    const int h    = blockIdx.y;
    const int b    = blockIdx.z;
    const int bh   = b * Hc + h;
    const int rt   = blockIdx.x * 4 + w;     // this wave's row tile 0..11

    __shared__ float kl[Tc], vl[Tc];         // 6 KB: k,v for whole (b,h)

#pragma unroll
    for (int r = 0; r < 3; ++r) {
        const int t = tid + 256 * r;
        kl[t] = ks[(size_t)bh * Tc + t];
        vl[t] = vs[(size_t)bh * Tc + t];
    }
    __syncthreads();

    const int i = rt * 64 + lane;
    const float q2 = qs[(size_t)bh * Tc + i];    // q * log2e
    const float slope2 = exp2f(-0.125f * (float)(h + 1)) * LOG2E;
    const float fi2 = slope2 * (float)i;

    // ---- Taylor powers: p_m = q^m / m!  (q natural = q2 * ln2) ----
    const float z = q2 * LN2;
    const float p1 = z;
    const float p2 = z * p1 * 0.5f;
    const float p3 = z * p2 * (1.f / 3.f);
    const float p4 = z * p3 * 0.25f;
    const float p5 = z * p4 * 0.2f;
    const float p6 = z * p5 * (1.f / 6.f);
    const float p7 = z * p6 * (1.f / 7.f);

    // ---- FUTURE: suffix moments (wave-uniform s_load) ----
    const float* __restrict__ sf = SufF + (size_t)bh * (NT * 16) + rt * 16;
    float S = sf[0];
    S = fmaf(p1, sf[1], S); S = fmaf(p2, sf[2], S); S = fmaf(p3, sf[3], S);
    S = fmaf(p4, sf[4], S); S = fmaf(p5, sf[5], S); S = fmaf(p6, sf[6], S);
    S = fmaf(p7, sf[7], S);
    float A = sf[8];
    A = fmaf(p1, sf[9],  A); A = fmaf(p2, sf[10], A); A = fmaf(p3, sf[11], A);
    A = fmaf(p4, sf[12], A); A = fmaf(p5, sf[13], A); A = fmaf(p6, sf[14], A);
    A = fmaf(p7, sf[15], A);

    // ---- PAST blocks: decayed moments, 1 exp per block ----
    for (int B = 0; B < rt; ++B) {
        const float dmin = slope2 * (float)(rt * 64 - (B * 64 + 63)); // >0
        if (dmin > 28.f) continue;           // wave-uniform ALiBi skip
        const float* __restrict__ pm_ = PMc + (size_t)bh * (NT * 16) + B * 16;
        const float f = exp2f(slope2 * (float)(B * 64 + 63) - fi2); // 2^(s(eB-i))
        float pS = pm_[0];
        pS = fmaf(p1, pm_[1], pS); pS = fmaf(p2, pm_[2], pS);
        pS = fmaf(p3, pm_[3], pS); pS = fmaf(p4, pm_[4], pS);
        pS = fmaf(p5, pm_[5], pS); pS = fmaf(p6, pm_[6], pS);
        pS = fmaf(p7, pm_[7], pS);
        float pA = pm_[8];
        pA = fmaf(p1, pm_[9],  pA); pA = fmaf(p2, pm_[10], pA);
        pA = fmaf(p3, pm_[11], pA); pA = fmaf(p4, pm_[12], pA);
        pA = fmaf(p5, pm_[13], pA); pA = fmaf(p6, pm_[14], pA);
        pA = fmaf(p7, pm_[15], pA);
        S = fmaf(f, pS, S);
        A = fmaf(f, pA, A);
    }

    // ---- DIAGONAL tile: exact (R13 inner, 4 sub-chunks of 16 j) ----
    v2f cu2[8];
#pragma unroll
    for (int u = 0; u < 8; ++u) {
        cu2[u].x = slope2 * (float)(2 * u);
        cu2[u].y = slope2 * (float)(2 * u + 1);
    }
    const int jd = rt * 64;
    const float mbd = slope2 * (float)jd - fi2;      // slope2*(jd - i) <= 0
    const v2f q2v = {q2, q2};
    v2f sum2 = {0.f, 0.f}, acc2 = {0.f, 0.f};
    const v2f* __restrict__ k2p = (const v2f*)&kl[jd];
    const v2f* __restrict__ v2p = (const v2f*)&vl[jd];
#pragma unroll
    for (int cc = 0; cc < 4; ++cc) {
        const float mbc = mbd + slope2 * (float)(16 * cc);
        const v2f mb2 = {mbc, mbc};
#pragma unroll
        for (int u = 0; u < 8; ++u) {
            v2f k2 = k2p[8 * cc + u];
            v2f v2 = v2p[8 * cc + u];
            v2f t2 = mb2 + cu2[u];
            v2f bias;
            bias.x = fminf(t2.x, 0.f);
            bias.y = fminf(t2.y, 0.f);
            v2f sc = q2v * k2 + bias;
            v2f e;
            e.x = __builtin_amdgcn_exp2f(sc.x);
            e.y = __builtin_amdgcn_exp2f(sc.y);
            sum2 += e;
            acc2 = e * v2 + acc2;
        }
    }
    S += sum2.x + sum2.y;
    A += acc2.x + acc2.y;

    out[((size_t)(b * Tc + i)) * 64 + h] = A * __builtin_amdgcn_rcpf(S);
}

extern "C" void kernel_launch(void* const* d_in, const int* in_sizes, int n_in,
                              void* d_out, int out_size, void* d_ws, size_t ws_size,
                              hipStream_t stream) {
    const float* x    = (const float*)d_in[0];
    const float* W    = (const float*)d_in[1];
    const float* vtmp = (const float*)d_in[2];
    const float* ptmp = (const float*)d_in[3];
    float* out = (float*)d_out;

    float* qsl  = (float*)d_ws;
    float* ksl  = qsl + SLAB;
    float* vsl  = ksl + SLAB;
    float* sufF = vsl + SLAB;          // [bh][12][16]
    float* pmc  = sufF + MOMSZ;        // [bh][12][16]

    proj_kernel<<<dim3(24, 16), 256, 0, stream>>>(x, W, vtmp, ptmp, qsl, ksl, vsl);
    moments_kernel<<<dim3(Bc * Hc), 256, 0, stream>>>(ksl, vsl, sufF, pmc);
    attn_kernel<<<dim3(3, Hc, Bc), 256, 0, stream>>>(qsl, ksl, vsl, sufF, pmc, out);
}

// Round 17
// 69.030 us; speedup vs baseline: 1.1775x; 1.1067x over previous
//
#include <hip/hip_runtime.h>
#include <stdint.h>

// Problem: B,T,C = 2,768,64; N_HEAD=64 -> head_dim=1; fp32 buffers.
// R16 verified the moment factorization math (absmax 1.2e-4): off-diagonal
// 64-j blocks collapse to 8 Taylor moments (deg-7, |qk|<~0.6, err ~1e-7).
// R16's cost miss: 1-wave/SIMD moments kernel + 11 serial guarded s_loads in
// attn + 3rd launch gap. R17: moments fused into proj (wave layout = exactly
// one (b,h,block) cell), attn at 6 blocks/CU with 4-way off-diag split, and
// branch-free past loop (exp2 underflow replaces the ALiBi skip).
constexpr int Tc = 768;
constexpr int Hc = 64;
constexpr int Bc = 2;
constexpr int NT = 12;                 // 64-wide j-blocks per sequence
constexpr float LOG2E = 1.44269504088896f;
constexpr float LN2   = 0.69314718056f;
constexpr size_t SLAB = (size_t)Bc * Hc * Tc;        // 98304 floats
constexpr size_t MOMS = (size_t)Bc * Hc * NT * 32;   // 49152 floats

typedef float v2f __attribute__((ext_vector_type(2)));
typedef float v4f __attribute__((ext_vector_type(4)));

// 64-lane DPP sum; total lands in lane 63 (verified R3/R8/R16).
__device__ __forceinline__ float dpp_reduce_add(float v) {
    v += __int_as_float(__builtin_amdgcn_update_dpp(0, __float_as_int(v), 0x111, 0xf, 0xf, true));
    v += __int_as_float(__builtin_amdgcn_update_dpp(0, __float_as_int(v), 0x112, 0xf, 0xf, true));
    v += __int_as_float(__builtin_amdgcn_update_dpp(0, __float_as_int(v), 0x114, 0xf, 0xf, true));
    v += __int_as_float(__builtin_amdgcn_update_dpp(0, __float_as_int(v), 0x118, 0xf, 0xf, true));
    v += __int_as_float(__builtin_amdgcn_update_dpp(0, __float_as_int(v), 0x142, 0xf, 0xf, true));
    v += __int_as_float(__builtin_amdgcn_update_dpp(0, __float_as_int(v), 0x143, 0xf, 0xf, true));
    return v;
}

// ---------------------------------------------------------------------------
// Kernel A: projection + per-block moments. grid (24,16) x 256.
// Wave = (b = bx/12, j-block B = bx%12, head h = by*4+w); lane = j in block.
//   qs/ks/vs as before (measured ~3 us).
//   MOM[bh][B][0..7]=FM_m=sum k^m, [8..15]=FMv_m=sum k^m v,
//            [16..23]=PM_m=sum k^m 2^{s(j-eB)}, [24..31]=PMv_m (eB=B*64+63).
// ---------------------------------------------------------------------------
__global__ __launch_bounds__(256) void proj_mom_kernel(
    const float* __restrict__ x, const float* __restrict__ W,
    const float* __restrict__ vtmp, const float* __restrict__ ptmp,
    float* __restrict__ qs, float* __restrict__ ks, float* __restrict__ vs,
    float* __restrict__ MOM)
{
    const int lane = threadIdx.x & 63;
    const int w    = __builtin_amdgcn_readfirstlane(threadIdx.x >> 6);
    const int bx   = blockIdx.x;
    const int b    = bx / NT;                    // 0..1
    const int B    = bx - b * NT;                // j-block 0..11
    const int t    = B * 64 + lane;
    const int g    = bx * 64 + lane;             // row in x
    const int h    = blockIdx.y * 4 + w;         // wave-uniform head
    const int bh   = b * Hc + h;

    float xr[64];
    const v4f* xp = (const v4f*)(x + (size_t)g * 64);
#pragma unroll
    for (int c = 0; c < 16; ++c) ((v4f*)xr)[c] = xp[c];

    const float* __restrict__ wq = W + h * 64;
    const float* __restrict__ wk = W + (64 + h) * 64;
    float aq = 0.f, ak = 0.f;
#pragma unroll
    for (int c = 0; c < 64; ++c) {               // constant indices only (R6)
        aq = fmaf(xr[c], wq[c], aq);
        ak = fmaf(xr[c], wk[c], ak);
    }
    const float vv = x[(size_t)g * 64 + h] * vtmp[h] * ptmp[h];
    const size_t o = (size_t)bh * Tc + t;        // lane-coalesced
    qs[o] = aq * LOG2E;
    ks[o] = ak;
    vs[o] = vv;

    // ---- moments of this (b,h,B) cell ----
    const float slope2 = exp2f(-0.125f * (float)(h + 1)) * LOG2E;
    const float lf = exp2f(slope2 * (float)(lane - 63));   // 2^{s(j-eB)} <= 1
    float rm[32];
    float km = 1.f;
#pragma unroll
    for (int m = 0; m < 8; ++m) {                // 4 independent DPP chains/m
        rm[m]      = dpp_reduce_add(km);
        rm[8 + m]  = dpp_reduce_add(km * vv);
        rm[16 + m] = dpp_reduce_add(km * lf);
        rm[24 + m] = dpp_reduce_add(km * lf * vv);
        km *= ak;
    }
    if (lane == 63) {
        float* mp = MOM + ((size_t)bh * NT + B) * 32;
#pragma unroll
        for (int m = 0; m < 32; ++m) mp[m] = rm[m];
    }
}

// ---------------------------------------------------------------------------
// Kernel B: attention via moments. grid (12,64,2) x 256 = 6 blocks/CU.
// Block = 64-row tile rt of (b,h); lane = row i. Wave w: diagonal j-slice
// [rt*64+16w, +16) exact (8 packed iters) + off-diag blocks B==w (mod 4),
// B != rt: future -> 16 FMA with FM; past -> f=2^{s(eB-i)} (underflows to 0
// for distant blocks: branch-free) + 16 FMA with PM. Partials via 2.5KB LDS.
// ---------------------------------------------------------------------------
__global__ __launch_bounds__(256, 6) void attn_kernel(
    const float* __restrict__ qs, const float* __restrict__ ks,
    const float* __restrict__ vs, const float* __restrict__ MOM,
    float* __restrict__ out)
{
    const int tid  = threadIdx.x;
    const int lane = tid & 63;
    const int w    = __builtin_amdgcn_readfirstlane(tid >> 6);
    const int rt   = blockIdx.x;     // 0..11
    const int h    = blockIdx.y;
    const int b    = blockIdx.z;
    const int bh   = b * Hc + h;

    __shared__ float kd[64], vd[64];             // diagonal tile k/v
    __shared__ float psum[4][64], pacc[4][64];

    if (tid < 64)       kd[tid]      = ks[(size_t)bh * Tc + rt * 64 + tid];
    else if (tid < 128) vd[tid - 64] = vs[(size_t)bh * Tc + rt * 64 + tid - 64];

    const int i = rt * 64 + lane;
    const float q2 = qs[(size_t)bh * Tc + i];    // q * log2e (coalesced)
    const float slope2 = exp2f(-0.125f * (float)(h + 1)) * LOG2E;
    const float fi2 = slope2 * (float)i;

    // Taylor p_m = q^m/m!  (q natural = q2*ln2)
    const float z  = q2 * LN2;
    const float p1 = z;
    const float p2 = z * p1 * 0.5f;
    const float p3 = z * p2 * (1.f / 3.f);
    const float p4 = z * p3 * 0.25f;
    const float p5 = z * p4 * 0.2f;
    const float p6 = z * p5 * (1.f / 6.f);
    const float p7 = z * p6 * (1.f / 7.f);

    float S = 0.f, A = 0.f;

    // ---- off-diagonal blocks (branch on B>rt is wave-uniform) ----
    for (int B = w; B < NT; B += 4) {
        if (B == rt) continue;
        const float* __restrict__ mp = MOM + ((size_t)bh * NT + B) * 32;  // s_load
        if (B > rt) {
            // FUTURE: bias = 0 -> plain moments
            float s0 = mp[0], a0 = mp[8];
            s0 = fmaf(p1, mp[1], s0);  a0 = fmaf(p1, mp[9],  a0);
            s0 = fmaf(p2, mp[2], s0);  a0 = fmaf(p2, mp[10], a0);
            s0 = fmaf(p3, mp[3], s0);  a0 = fmaf(p3, mp[11], a0);
            s0 = fmaf(p4, mp[4], s0);  a0 = fmaf(p4, mp[12], a0);
            s0 = fmaf(p5, mp[5], s0);  a0 = fmaf(p5, mp[13], a0);
            s0 = fmaf(p6, mp[6], s0);  a0 = fmaf(p6, mp[14], a0);
            s0 = fmaf(p7, mp[7], s0);  a0 = fmaf(p7, mp[15], a0);
            S += s0;  A += a0;
        } else {
            // PAST: decayed moments; f underflows to exact 0 for far blocks
            const float f = exp2f(slope2 * (float)(B * 64 + 63) - fi2);
            float s0 = mp[16], a0 = mp[24];
            s0 = fmaf(p1, mp[17], s0); a0 = fmaf(p1, mp[25], a0);
            s0 = fmaf(p2, mp[18], s0); a0 = fmaf(p2, mp[26], a0);
            s0 = fmaf(p3, mp[19], s0); a0 = fmaf(p3, mp[27], a0);
            s0 = fmaf(p4, mp[20], s0); a0 = fmaf(p4, mp[28], a0);
            s0 = fmaf(p5, mp[21], s0); a0 = fmaf(p5, mp[29], a0);
            s0 = fmaf(p6, mp[22], s0); a0 = fmaf(p6, mp[30], a0);
            s0 = fmaf(p7, mp[23], s0); a0 = fmaf(p7, mp[31], a0);
            S = fmaf(f, s0, S);  A = fmaf(f, a0, A);
        }
    }

    __syncthreads();

    // ---- diagonal slice: wave w covers j in [rt*64+16w, +16), exact ----
    v2f cu2[8];
#pragma unroll
    for (int u = 0; u < 8; ++u) {
        cu2[u].x = slope2 * (float)(2 * u);
        cu2[u].y = slope2 * (float)(2 * u + 1);
    }
    const float mb = slope2 * (float)(rt * 64 + 16 * w) - fi2;  // s*(jw - i)
    const v2f mb2 = {mb, mb};
    const v2f q2v = {q2, q2};
    v2f sum2 = {0.f, 0.f}, acc2 = {0.f, 0.f};
    const v2f* __restrict__ k2p = (const v2f*)kd;
    const v2f* __restrict__ v2p = (const v2f*)vd;
#pragma unroll
    for (int u = 0; u < 8; ++u) {
        v2f k2 = k2p[8 * w + u];                 // ds_read_b64 broadcast
        v2f v2 = v2p[8 * w + u];
        v2f t2 = mb2 + cu2[u];
        v2f bias;
        bias.x = fminf(t2.x, 0.f);
        bias.y = fminf(t2.y, 0.f);
        v2f sc = q2v * k2 + bias;
        v2f e;
        e.x = __builtin_amdgcn_exp2f(sc.x);
        e.y = __builtin_amdgcn_exp2f(sc.y);
        sum2 += e;
        acc2 = e * v2 + acc2;
    }
    S += sum2.x + sum2.y;
    A += acc2.x + acc2.y;

    psum[w][lane] = S;
    pacc[w][lane] = A;
    __syncthreads();

    if (tid < 64) {
        float s = psum[0][lane] + psum[1][lane] + psum[2][lane] + psum[3][lane];
        float a = pacc[0][lane] + pacc[1][lane] + pacc[2][lane] + pacc[3][lane];
        out[((size_t)(b * Tc + rt * 64 + lane)) * 64 + h] =
            a * __builtin_amdgcn_rcpf(s);
    }
}

extern "C" void kernel_launch(void* const* d_in, const int* in_sizes, int n_in,
                              void* d_out, int out_size, void* d_ws, size_t ws_size,
                              hipStream_t stream) {
    const float* x    = (const float*)d_in[0];
    const float* W    = (const float*)d_in[1];
    const float* vtmp = (const float*)d_in[2];
    const float* ptmp = (const float*)d_in[3];
    float* out = (float*)d_out;

    float* qsl = (float*)d_ws;
    float* ksl = qsl + SLAB;
    float* vsl = ksl + SLAB;
    float* mom = vsl + SLAB;           // [bh][12][32]

    proj_mom_kernel<<<dim3(24, 16), 256, 0, stream>>>(
        x, W, vtmp, ptmp, qsl, ksl, vsl, mom);
    attn_kernel<<<dim3(NT, Hc, Bc), 256, 0, stream>>>(
        qsl, ksl, vsl, mom, out);
}

// Round 18
// 68.922 us; speedup vs baseline: 1.1794x; 1.0016x over previous
//
#include <hip/hip_runtime.h>
#include <stdint.h>

// Problem: B,T,C = 2,768,64; N_HEAD=64 -> head_dim=1; fp32 buffers.
// R17 (69.0 us) validated fused moment factorization (absmax 1.2e-4).
// Residual analysis: proj_mom ~11 us of the 15.5 us kernel budget — caused
// by (a) 8 SERIAL moment-chain groups (km *= ak dependency) x ~6-step DPP
// latency un-hidden, (b) grid 384 blocks = 1.5 blocks/CU imbalanced (2:1).
// R18: precompute all k^m powers, then 32 INDEPENDENT chains advanced in 6
// step-synchronous DPP passes (32-wide ILP); grid (24 bB, 64 h) x 64 thr =
// 1536 single-wave blocks = 6 waves/CU exact. attn kernel unchanged (R17).
constexpr int Tc = 768;
constexpr int Hc = 64;
constexpr int Bc = 2;
constexpr int NT = 12;                 // 64-wide j-blocks per sequence
constexpr float LOG2E = 1.44269504088896f;
constexpr float LN2   = 0.69314718056f;
constexpr size_t SLAB = (size_t)Bc * Hc * Tc;        // 98304 floats

typedef float v2f __attribute__((ext_vector_type(2)));
typedef float v4f __attribute__((ext_vector_type(4)));

// 64-lane DPP sum (verified R3/R8/R16/R17); total lands in lane 63.
__device__ __forceinline__ float dpp_reduce_add(float v) {
    v += __int_as_float(__builtin_amdgcn_update_dpp(0, __float_as_int(v), 0x111, 0xf, 0xf, true));
    v += __int_as_float(__builtin_amdgcn_update_dpp(0, __float_as_int(v), 0x112, 0xf, 0xf, true));
    v += __int_as_float(__builtin_amdgcn_update_dpp(0, __float_as_int(v), 0x114, 0xf, 0xf, true));
    v += __int_as_float(__builtin_amdgcn_update_dpp(0, __float_as_int(v), 0x118, 0xf, 0xf, true));
    v += __int_as_float(__builtin_amdgcn_update_dpp(0, __float_as_int(v), 0x142, 0xf, 0xf, true));
    v += __int_as_float(__builtin_amdgcn_update_dpp(0, __float_as_int(v), 0x143, 0xf, 0xf, true));
    return v;
}

// ---------------------------------------------------------------------------
// Kernel A: projection + per-block moments. grid (24, 64) x 64 threads:
// block = one (b, j-block B, head h) cell; lane = j within block.
//   qs[(b*64+h)*768+t] = LOG2E * q;  ks = k;  vs = x[..,h]*vtmp*ptmp
//   MOM[bh][B][0..7]=sum k^m, [8..15]=sum k^m v,
//            [16..23]=sum k^m 2^{s(j-eB)}, [24..31]=sum k^m 2^{s(j-eB)} v.
// 1536 blocks = 6 waves/CU exact; 32 reduction chains advance in lock-step
// (6 DPP passes, 32-wide ILP) so cross-lane latency is pipeline-hidden.
// ---------------------------------------------------------------------------
__global__ __launch_bounds__(64) void proj_mom_kernel(
    const float* __restrict__ x, const float* __restrict__ W,
    const float* __restrict__ vtmp, const float* __restrict__ ptmp,
    float* __restrict__ qs, float* __restrict__ ks, float* __restrict__ vs,
    float* __restrict__ MOM)
{
    const int lane = threadIdx.x & 63;
    const int bx   = blockIdx.x;                 // 0..23 = b*12 + B
    const int b    = bx / NT;
    const int B    = bx - b * NT;
    const int t    = B * 64 + lane;
    const int g    = bx * 64 + lane;             // row in x (b*768 + t)
    const int h    = blockIdx.y;                 // scalar (block-uniform)
    const int bh   = b * Hc + h;

    // ---- projection dots (running 4-wide, no 64-reg array) ----
    const v4f* xp = (const v4f*)(x + (size_t)g * 64);
    const float* __restrict__ wq = W + h * 64;
    const float* __restrict__ wk = W + (64 + h) * 64;
    float aq = 0.f, ak = 0.f;
#pragma unroll
    for (int c = 0; c < 16; ++c) {
        v4f u = xp[c];
        aq = fmaf(u.x, wq[4*c],   aq);  ak = fmaf(u.x, wk[4*c],   ak);
        aq = fmaf(u.y, wq[4*c+1], aq);  ak = fmaf(u.y, wk[4*c+1], ak);
        aq = fmaf(u.z, wq[4*c+2], aq);  ak = fmaf(u.z, wk[4*c+2], ak);
        aq = fmaf(u.w, wq[4*c+3], aq);  ak = fmaf(u.w, wk[4*c+3], ak);
    }
    const float vv = x[(size_t)g * 64 + h] * vtmp[h] * ptmp[h];
    const size_t o = (size_t)bh * Tc + t;        // lane-coalesced
    qs[o] = aq * LOG2E;
    ks[o] = ak;
    vs[o] = vv;

    // ---- moments: 32 independent chains, step-synchronous DPP passes ----
    const float slope2 = exp2f(-0.125f * (float)(h + 1)) * LOG2E;
    const float lf = exp2f(slope2 * (float)(lane - 63));   // 2^{s(j-eB)} <= 1

    float km[8];
    km[0] = 1.f;
#pragma unroll
    for (int m = 1; m < 8; ++m) km[m] = km[m - 1] * ak;    // 7 serial muls only

    float r[32];
#pragma unroll
    for (int m = 0; m < 8; ++m) {
        const float kl2 = km[m] * lf;
        r[m]      = km[m];
        r[8 + m]  = km[m] * vv;
        r[16 + m] = kl2;
        r[24 + m] = kl2 * vv;
    }
#define DPP_PASS(CTRL)                                                        \
    _Pragma("unroll")                                                         \
    for (int ii = 0; ii < 32; ++ii)                                           \
        r[ii] += __int_as_float(__builtin_amdgcn_update_dpp(                  \
            0, __float_as_int(r[ii]), CTRL, 0xf, 0xf, true));
    DPP_PASS(0x111)   // row_shr:1
    DPP_PASS(0x112)   // row_shr:2
    DPP_PASS(0x114)   // row_shr:4
    DPP_PASS(0x118)   // row_shr:8
    DPP_PASS(0x142)   // row_bcast:15
    DPP_PASS(0x143)   // row_bcast:31
#undef DPP_PASS

    if (lane == 63) {
        float* mp = MOM + ((size_t)bh * NT + B) * 32;
#pragma unroll
        for (int m = 0; m < 8; ++m) {            // 8x dwordx4 stores
            v4f s4 = { r[4*m], r[4*m+1], r[4*m+2], r[4*m+3] };
            *(v4f*)(mp + 4 * m) = s4;
        }
    }
}

// ---------------------------------------------------------------------------
// Kernel B: attention via moments (unchanged from R17, validated).
// grid (12,64,2) x 256 = 6 blocks/CU. Block = 64-row tile rt of (b,h);
// lane = row i. Wave w: diagonal slice [rt*64+16w,+16) exact + off-diag
// blocks B = w mod 4 (future: plain moments; past: f=2^{s(eB-i)} decayed,
// underflow-to-0 replaces ALiBi skip, branch-free).
// ---------------------------------------------------------------------------
__global__ __launch_bounds__(256, 6) void attn_kernel(
    const float* __restrict__ qs, const float* __restrict__ ks,
    const float* __restrict__ vs, const float* __restrict__ MOM,
    float* __restrict__ out)
{
    const int tid  = threadIdx.x;
    const int lane = tid & 63;
    const int w    = __builtin_amdgcn_readfirstlane(tid >> 6);
    const int rt   = blockIdx.x;     // 0..11
    const int h    = blockIdx.y;
    const int b    = blockIdx.z;
    const int bh   = b * Hc + h;

    __shared__ float kd[64], vd[64];             // diagonal tile k/v
    __shared__ float psum[4][64], pacc[4][64];

    if (tid < 64)       kd[tid]      = ks[(size_t)bh * Tc + rt * 64 + tid];
    else if (tid < 128) vd[tid - 64] = vs[(size_t)bh * Tc + rt * 64 + tid - 64];

    const int i = rt * 64 + lane;
    const float q2 = qs[(size_t)bh * Tc + i];    // q * log2e (coalesced)
    const float slope2 = exp2f(-0.125f * (float)(h + 1)) * LOG2E;
    const float fi2 = slope2 * (float)i;

    // Taylor p_m = q^m/m!  (q natural = q2*ln2)
    const float z  = q2 * LN2;
    const float p1 = z;
    const float p2 = z * p1 * 0.5f;
    const float p3 = z * p2 * (1.f / 3.f);
    const float p4 = z * p3 * 0.25f;
    const float p5 = z * p4 * 0.2f;
    const float p6 = z * p5 * (1.f / 6.f);
    const float p7 = z * p6 * (1.f / 7.f);

    float S = 0.f, A = 0.f;

    // ---- off-diagonal blocks (wave-uniform control flow) ----
    for (int B = w; B < NT; B += 4) {
        if (B == rt) continue;
        const float* __restrict__ mp = MOM + ((size_t)bh * NT + B) * 32;  // s_load
        if (B > rt) {
            // FUTURE: bias = 0 -> plain moments
            float s0 = mp[0], a0 = mp[8];
            s0 = fmaf(p1, mp[1], s0);  a0 = fmaf(p1, mp[9],  a0);
            s0 = fmaf(p2, mp[2], s0);  a0 = fmaf(p2, mp[10], a0);
            s0 = fmaf(p3, mp[3], s0);  a0 = fmaf(p3, mp[11], a0);
            s0 = fmaf(p4, mp[4], s0);  a0 = fmaf(p4, mp[12], a0);
            s0 = fmaf(p5, mp[5], s0);  a0 = fmaf(p5, mp[13], a0);
            s0 = fmaf(p6, mp[6], s0);  a0 = fmaf(p6, mp[14], a0);
            s0 = fmaf(p7, mp[7], s0);  a0 = fmaf(p7, mp[15], a0);
            S += s0;  A += a0;
        } else {
            // PAST: decayed moments; f underflows to exact 0 for far blocks
            const float f = exp2f(slope2 * (float)(B * 64 + 63) - fi2);
            float s0 = mp[16], a0 = mp[24];
            s0 = fmaf(p1, mp[17], s0); a0 = fmaf(p1, mp[25], a0);
            s0 = fmaf(p2, mp[18], s0); a0 = fmaf(p2, mp[26], a0);
            s0 = fmaf(p3, mp[19], s0); a0 = fmaf(p3, mp[27], a0);
            s0 = fmaf(p4, mp[20], s0); a0 = fmaf(p4, mp[28], a0);
            s0 = fmaf(p5, mp[21], s0); a0 = fmaf(p5, mp[29], a0);
            s0 = fmaf(p6, mp[22], s0); a0 = fmaf(p6, mp[30], a0);
            s0 = fmaf(p7, mp[23], s0); a0 = fmaf(p7, mp[31], a0);
            S = fmaf(f, s0, S);  A = fmaf(f, a0, A);
        }
    }

    __syncthreads();

    // ---- diagonal slice: wave w covers j in [rt*64+16w, +16), exact ----
    v2f cu2[8];
#pragma unroll
    for (int u = 0; u < 8; ++u) {
        cu2[u].x = slope2 * (float)(2 * u);
        cu2[u].y = slope2 * (float)(2 * u + 1);
    }
    const float mb = slope2 * (float)(rt * 64 + 16 * w) - fi2;  // s*(jw - i)
    const v2f mb2 = {mb, mb};
    const v2f q2v = {q2, q2};
    v2f sum2 = {0.f, 0.f}, acc2 = {0.f, 0.f};
    const v2f* __restrict__ k2p = (const v2f*)kd;
    const v2f* __restrict__ v2p = (const v2f*)vd;
#pragma unroll
    for (int u = 0; u < 8; ++u) {
        v2f k2 = k2p[8 * w + u];                 // ds_read_b64 broadcast
        v2f v2 = v2p[8 * w + u];
        v2f t2 = mb2 + cu2[u];
        v2f bias;
        bias.x = fminf(t2.x, 0.f);
        bias.y = fminf(t2.y, 0.f);
        v2f sc = q2v * k2 + bias;
        v2f e;
        e.x = __builtin_amdgcn_exp2f(sc.x);
        e.y = __builtin_amdgcn_exp2f(sc.y);
        sum2 += e;
        acc2 = e * v2 + acc2;
    }
    S += sum2.x + sum2.y;
    A += acc2.x + acc2.y;

    psum[w][lane] = S;
    pacc[w][lane] = A;
    __syncthreads();

    if (tid < 64) {
        float s = psum[0][lane] + psum[1][lane] + psum[2][lane] + psum[3][lane];
        float a = pacc[0][lane] + pacc[1][lane] + pacc[2][lane] + pacc[3][lane];
        out[((size_t)(b * Tc + rt * 64 + lane)) * 64 + h] =
            a * __builtin_amdgcn_rcpf(s);
    }
}

extern "C" void kernel_launch(void* const* d_in, const int* in_sizes, int n_in,
                              void* d_out, int out_size, void* d_ws, size_t ws_size,
                              hipStream_t stream) {
    const float* x    = (const float*)d_in[0];
    const float* W    = (const float*)d_in[1];
    const float* vtmp = (const float*)d_in[2];
    const float* ptmp = (const float*)d_in[3];
    float* out = (float*)d_out;

    float* qsl = (float*)d_ws;
    float* ksl = qsl + SLAB;
    float* vsl = ksl + SLAB;
    float* mom = vsl + SLAB;           // [bh][12][32]

    proj_mom_kernel<<<dim3(24, Hc), 64, 0, stream>>>(
        x, W, vtmp, ptmp, qsl, ksl, vsl, mom);
    attn_kernel<<<dim3(NT, Hc, Bc), 256, 0, stream>>>(
        qsl, ksl, vsl, mom, out);
}

// Round 19
// 67.272 us; speedup vs baseline: 1.2083x; 1.0245x over previous
//
#include <hip/hip_runtime.h>
#include <stdint.h>

// Problem: B,T,C = 2,768,64; N_HEAD=64 -> head_dim=1; fp32 buffers.
// R18 flat => proj_mom was not the residual; attn's off-diag loop issued
// ~96 broadcast VMEM loads/wave (uniform-address mp[] not scalarized) plus
// 3x redundant Taylor evals. R19: suffix/prefix collapse — stage MOM[bh]
// (384 floats) in LDS, 32 threads build comb[32] = {future-suffix FM,
// past-prefix 2^{s(eB-r0)}-weighted PM}, then each row does exactly 2 moment
// evals (wave 0) + validated diag quarter. Off-diag VMEM per wave: 0.
constexpr int Tc = 768;
constexpr int Hc = 64;
constexpr int Bc = 2;
constexpr int NT = 12;                 // 64-wide j-blocks per sequence
constexpr float LOG2E = 1.44269504088896f;
constexpr float LN2   = 0.69314718056f;
constexpr size_t SLAB = (size_t)Bc * Hc * Tc;        // 98304 floats

typedef float v2f __attribute__((ext_vector_type(2)));
typedef float v4f __attribute__((ext_vector_type(4)));

// ---------------------------------------------------------------------------
// Kernel A: projection + per-block moments (R18, measured-adequate).
// grid (24, 64) x 64 thr = 1536 single-wave blocks = 6 waves/CU.
//   MOM[bh][B][0..7]=sum k^m, [8..15]=sum k^m v,
//            [16..23]=sum k^m 2^{s(j-eB)}, [24..31]=... * v   (eB=B*64+63)
// ---------------------------------------------------------------------------
__global__ __launch_bounds__(64) void proj_mom_kernel(
    const float* __restrict__ x, const float* __restrict__ W,
    const float* __restrict__ vtmp, const float* __restrict__ ptmp,
    float* __restrict__ qs, float* __restrict__ ks, float* __restrict__ vs,
    float* __restrict__ MOM)
{
    const int lane = threadIdx.x & 63;
    const int bx   = blockIdx.x;                 // 0..23 = b*12 + B
    const int b    = bx / NT;
    const int B    = bx - b * NT;
    const int t    = B * 64 + lane;
    const int g    = bx * 64 + lane;             // row in x (b*768 + t)
    const int h    = blockIdx.y;                 // block-uniform
    const int bh   = b * Hc + h;

    const v4f* xp = (const v4f*)(x + (size_t)g * 64);
    const float* __restrict__ wq = W + h * 64;
    const float* __restrict__ wk = W + (64 + h) * 64;
    float aq = 0.f, ak = 0.f;
#pragma unroll
    for (int c = 0; c < 16; ++c) {
        v4f u = xp[c];
        aq = fmaf(u.x, wq[4*c],   aq);  ak = fmaf(u.x, wk[4*c],   ak);
        aq = fmaf(u.y, wq[4*c+1], aq);  ak = fmaf(u.y, wk[4*c+1], ak);
        aq = fmaf(u.z, wq[4*c+2], aq);  ak = fmaf(u.z, wk[4*c+2], ak);
        aq = fmaf(u.w, wq[4*c+3], aq);  ak = fmaf(u.w, wk[4*c+3], ak);
    }
    const float vv = x[(size_t)g * 64 + h] * vtmp[h] * ptmp[h];
    const size_t o = (size_t)bh * Tc + t;        // lane-coalesced
    qs[o] = aq * LOG2E;
    ks[o] = ak;
    vs[o] = vv;

    const float slope2 = exp2f(-0.125f * (float)(h + 1)) * LOG2E;
    const float lf = exp2f(slope2 * (float)(lane - 63));   // 2^{s(j-eB)} <= 1

    float km[8];
    km[0] = 1.f;
#pragma unroll
    for (int m = 1; m < 8; ++m) km[m] = km[m - 1] * ak;

    float r[32];
#pragma unroll
    for (int m = 0; m < 8; ++m) {
        const float kl2 = km[m] * lf;
        r[m]      = km[m];
        r[8 + m]  = km[m] * vv;
        r[16 + m] = kl2;
        r[24 + m] = kl2 * vv;
    }
#define DPP_PASS(CTRL)                                                        \
    _Pragma("unroll")                                                         \
    for (int ii = 0; ii < 32; ++ii)                                           \
        r[ii] += __int_as_float(__builtin_amdgcn_update_dpp(                  \
            0, __float_as_int(r[ii]), CTRL, 0xf, 0xf, true));
    DPP_PASS(0x111)
    DPP_PASS(0x112)
    DPP_PASS(0x114)
    DPP_PASS(0x118)
    DPP_PASS(0x142)
    DPP_PASS(0x143)
#undef DPP_PASS

    if (lane == 63) {
        float* mp = MOM + ((size_t)bh * NT + B) * 32;
#pragma unroll
        for (int m = 0; m < 8; ++m) {
            v4f s4 = { r[4*m], r[4*m+1], r[4*m+2], r[4*m+3] };
            *(v4f*)(mp + 4 * m) = s4;
        }
    }
}

// ---------------------------------------------------------------------------
// Kernel B: attention, suffix/prefix-collapsed moments.
// grid (12,64,2) x 256 = 6 blocks/CU. Block = 64-row tile rt of (b,h).
//  stage: MOM[bh] (384 f) + diag k/v (128 f) -> LDS.
//  comb[32] by 32 threads: [0..15] = sum_{B>rt} FM/FMv[m];
//                          [16..31] = sum_{B<rt} 2^{s(64(B-rt)+63)} PM/PMv[m].
//  per row (lane): wave0 adds off-diag = suf-eval + 2^{-s*lane} * pre-eval;
//  each wave computes its validated 16-j diagonal quarter (exact exp2).
// ---------------------------------------------------------------------------
__global__ __launch_bounds__(256, 6) void attn_kernel(
    const float* __restrict__ qs, const float* __restrict__ ks,
    const float* __restrict__ vs, const float* __restrict__ MOM,
    float* __restrict__ out)
{
    const int tid  = threadIdx.x;
    const int lane = tid & 63;
    const int w    = __builtin_amdgcn_readfirstlane(tid >> 6);
    const int rt   = blockIdx.x;     // 0..11
    const int h    = blockIdx.y;
    const int b    = blockIdx.z;
    const int bh   = b * Hc + h;

    __shared__ float momL[NT * 32];              // 1.5 KB
    __shared__ float kd[64], vd[64];
    __shared__ float comb[32];
    __shared__ float psum[4][64], pacc[4][64];

    // ---- stage: moments + diag k/v (coalesced) ----
    {
        const float* __restrict__ mbp = MOM + (size_t)bh * (NT * 32);
        if (tid < 128) {
            momL[tid]       = mbp[tid];
            momL[tid + 128] = mbp[tid + 128];
            momL[tid + 256] = mbp[tid + 256];
        } else if (tid < 192) {
            kd[tid - 128] = ks[(size_t)bh * Tc + rt * 64 + (tid - 128)];
        } else {
            vd[tid - 192] = vs[(size_t)bh * Tc + rt * 64 + (tid - 192)];
        }
    }
    const float slope2 = exp2f(-0.125f * (float)(h + 1)) * LOG2E;
    __syncthreads();

    // ---- collapse blocks: 32 threads build comb ----
    if (tid < 32) {
        const int grp = tid >> 4;        // 0 = future suffix, 1 = past prefix
        const int m16 = tid & 15;
        float acc = 0.f;
        if (grp == 0) {
            for (int B = rt + 1; B < NT; ++B)
                acc += momL[B * 32 + m16];
        } else {
            for (int B = 0; B < rt; ++B)
                acc = fmaf(exp2f(slope2 * (float)(64 * (B - rt) + 63)),
                           momL[B * 32 + 16 + m16], acc);   // underflow->0 far
        }
        comb[tid] = acc;
    }
    __syncthreads();

    // ---- per-row state ----
    const int i = rt * 64 + lane;
    const float q2 = qs[(size_t)bh * Tc + i];    // q * log2e (coalesced)
    const float fi2 = slope2 * (float)i;

    // Taylor p_m = q^m/m!  (q natural = q2*ln2)
    const float z  = q2 * LN2;
    const float p1 = z;
    const float p2 = z * p1 * 0.5f;
    const float p3 = z * p2 * (1.f / 3.f);
    const float p4 = z * p3 * 0.25f;
    const float p5 = z * p4 * 0.2f;
    const float p6 = z * p5 * (1.f / 6.f);
    const float p7 = z * p6 * (1.f / 7.f);

    float S = 0.f, A = 0.f;
    if (w == 0) {
        // off-diagonal: one suffix eval + one weighted prefix eval
        float sf = comb[0];
        sf = fmaf(p1, comb[1], sf); sf = fmaf(p2, comb[2], sf);
        sf = fmaf(p3, comb[3], sf); sf = fmaf(p4, comb[4], sf);
        sf = fmaf(p5, comb[5], sf); sf = fmaf(p6, comb[6], sf);
        sf = fmaf(p7, comb[7], sf);
        float af = comb[8];
        af = fmaf(p1, comb[9],  af); af = fmaf(p2, comb[10], af);
        af = fmaf(p3, comb[11], af); af = fmaf(p4, comb[12], af);
        af = fmaf(p5, comb[13], af); af = fmaf(p6, comb[14], af);
        af = fmaf(p7, comb[15], af);
        float sp = comb[16];
        sp = fmaf(p1, comb[17], sp); sp = fmaf(p2, comb[18], sp);
        sp = fmaf(p3, comb[19], sp); sp = fmaf(p4, comb[20], sp);
        sp = fmaf(p5, comb[21], sp); sp = fmaf(p6, comb[22], sp);
        sp = fmaf(p7, comb[23], sp);
        float ap = comb[24];
        ap = fmaf(p1, comb[25], ap); ap = fmaf(p2, comb[26], ap);
        ap = fmaf(p3, comb[27], ap); ap = fmaf(p4, comb[28], ap);
        ap = fmaf(p5, comb[29], ap); ap = fmaf(p6, comb[30], ap);
        ap = fmaf(p7, comb[31], ap);
        const float f = __builtin_amdgcn_exp2f(-slope2 * (float)lane); // 2^{s(r0-i)}
        S = fmaf(f, sp, sf);
        A = fmaf(f, ap, af);
    }

    // ---- diagonal slice (validated R17/R18): wave w -> j in [r0+16w,+16) ----
    v2f cu2[8];
#pragma unroll
    for (int u = 0; u < 8; ++u) {
        cu2[u].x = slope2 * (float)(2 * u);
        cu2[u].y = slope2 * (float)(2 * u + 1);
    }
    const float mb = slope2 * (float)(rt * 64 + 16 * w) - fi2;  // s*(jw - i)
    const v2f mb2 = {mb, mb};
    const v2f q2v = {q2, q2};
    v2f sum2 = {0.f, 0.f}, acc2 = {0.f, 0.f};
    const v2f* __restrict__ k2p = (const v2f*)kd;
    const v2f* __restrict__ v2p = (const v2f*)vd;
#pragma unroll
    for (int u = 0; u < 8; ++u) {
        v2f k2 = k2p[8 * w + u];                 // ds_read_b64 broadcast
        v2f v2 = v2p[8 * w + u];
        v2f t2 = mb2 + cu2[u];
        v2f bias;
        bias.x = fminf(t2.x, 0.f);
        bias.y = fminf(t2.y, 0.f);
        v2f sc = q2v * k2 + bias;
        v2f e;
        e.x = __builtin_amdgcn_exp2f(sc.x);
        e.y = __builtin_amdgcn_exp2f(sc.y);
        sum2 += e;
        acc2 = e * v2 + acc2;
    }
    S += sum2.x + sum2.y;
    A += acc2.x + acc2.y;

    psum[w][lane] = S;
    pacc[w][lane] = A;
    __syncthreads();

    if (tid < 64) {
        float s = psum[0][lane] + psum[1][lane] + psum[2][lane] + psum[3][lane];
        float a = pacc[0][lane] + pacc[1][lane] + pacc[2][lane] + pacc[3][lane];
        out[((size_t)(b * Tc + rt * 64 + lane)) * 64 + h] =
            a * __builtin_amdgcn_rcpf(s);
    }
}

extern "C" void kernel_launch(void* const* d_in, const int* in_sizes, int n_in,
                              void* d_out, int out_size, void* d_ws, size_t ws_size,
                              hipStream_t stream) {
    const float* x    = (const float*)d_in[0];
    const float* W    = (const float*)d_in[1];
    const float* vtmp = (const float*)d_in[2];
    const float* ptmp = (const float*)d_in[3];
    float* out = (float*)d_out;

    float* qsl = (float*)d_ws;
    float* ksl = qsl + SLAB;
    float* vsl = ksl + SLAB;
    float* mom = vsl + SLAB;           // [bh][12][32]

    proj_mom_kernel<<<dim3(24, Hc), 64, 0, stream>>>(
        x, W, vtmp, ptmp, qsl, ksl, vsl, mom);
    attn_kernel<<<dim3(NT, Hc, Bc), 256, 0, stream>>>(
        qsl, ksl, vsl, mom, out);
}